// Round 1
// baseline (335.608 us; speedup 1.0000x reference)
//
#include <hip/hip_runtime.h>

typedef __bf16 bf16;
typedef __attribute__((ext_vector_type(8))) __bf16 bf16x8;
typedef __attribute__((ext_vector_type(4))) float f32x4;

constexpr int S_LEN = 2048;
constexpr int DH    = 64;
constexpr int QBLK  = 64;
constexpr int KVBLK = 64;
constexpr int NWAVE = 4;
constexpr float SCALE = 0.125f;               // 1/sqrt(64)
constexpr float LOG2E = 1.44269504088896f;

__device__ __forceinline__ ushort bfb(float f) {
  bf16 b = (bf16)f;
  return __builtin_bit_cast(ushort, b);
}

__device__ __forceinline__ float redmax16(float x) {
  x = fmaxf(x, __shfl_xor(x, 1));
  x = fmaxf(x, __shfl_xor(x, 2));
  x = fmaxf(x, __shfl_xor(x, 4));
  x = fmaxf(x, __shfl_xor(x, 8));
  return x;
}
__device__ __forceinline__ float redsum16(float x) {
  x += __shfl_xor(x, 1);
  x += __shfl_xor(x, 2);
  x += __shfl_xor(x, 4);
  x += __shfl_xor(x, 8);
  return x;
}

__global__ __launch_bounds__(256)
void attn_fwd(const float* __restrict__ Q, const float* __restrict__ K,
              const float* __restrict__ V, const int* __restrict__ M,
              float* __restrict__ O)
{
  // K: [kv][d] row-major bf16, 128B rows, XOR-swizzled (G4: stride-128B trap)
  // V: [d][kv] transposed bf16, swizzled  -> PV B-frags are contiguous b128
  // P: per-wave [16 q][64 kv] bf16, swizzled
  __shared__ __align__(16) ushort kbuf[KVBLK * DH];
  __shared__ __align__(16) ushort vbuf[DH * KVBLK];
  __shared__ __align__(16) ushort pbuf[NWAVE * 16 * KVBLK];

  const int tid  = threadIdx.x;
  const int lane = tid & 63;
  const int w    = tid >> 6;
  const int qr   = lane & 15;   // A-frag row / C-frag col
  const int kg   = lane >> 4;   // lane group 0..3

  const int q0 = blockIdx.x * QBLK;
  const int bh = blockIdx.y;

  const float* Qb = Q + ((size_t)bh * S_LEN) * DH;
  const float* Kb = K + ((size_t)bh * S_LEN) * DH;
  const float* Vb = V + ((size_t)bh * S_LEN) * DH;

  // ---- Q fragments in registers, pre-scaled by 1/8 (exact in bf16) ----
  bf16x8 qf[2];
  {
    const float* qp = Qb + (size_t)(q0 + w*16 + qr) * DH + kg*8;
#pragma unroll
    for (int ks = 0; ks < 2; ++ks) {
      float4 a = *(const float4*)(qp + ks*32);
      float4 b = *(const float4*)(qp + ks*32 + 4);
      bf16x8 t;
      t[0]=(bf16)(a.x*SCALE); t[1]=(bf16)(a.y*SCALE);
      t[2]=(bf16)(a.z*SCALE); t[3]=(bf16)(a.w*SCALE);
      t[4]=(bf16)(b.x*SCALE); t[5]=(bf16)(b.y*SCALE);
      t[6]=(bf16)(b.z*SCALE); t[7]=(bf16)(b.w*SCALE);
      qf[ks] = t;
    }
  }

  f32x4 acc[4];
#pragma unroll
  for (int nt = 0; nt < 4; ++nt) { f32x4 z = {0.f,0.f,0.f,0.f}; acc[nt] = z; }
  float mrow[4] = {-1e30f,-1e30f,-1e30f,-1e30f};
  float rsum[4] = {0.f,0.f,0.f,0.f};

  const int srow = tid >> 4;   // staging row within 16
  const int sc4  = tid & 15;   // staging float4 column

  for (int t = 0; t < S_LEN / KVBLK; ++t) {
    const int kv0 = t * KVBLK;
    __syncthreads();   // previous tile's K/V reads complete before overwrite

    // ---- stage K (row-major) and V (transposed), fp32->bf16, swizzled ----
#pragma unroll
    for (int i = 0; i < 4; ++i) {
      const int kv = srow + 16*i;
      const float4 kx = *(const float4*)(Kb + (size_t)(kv0+kv)*DH + sc4*4);
      const float4 vx = *(const float4*)(Vb + (size_t)(kv0+kv)*DH + sc4*4);
      union { uint2 u; ushort h[4]; } pk;
      pk.h[0] = bfb(kx.x); pk.h[1] = bfb(kx.y);
      pk.h[2] = bfb(kx.z); pk.h[3] = bfb(kx.w);
      *(uint2*)((char*)kbuf + kv*128 + ((sc4*8) ^ ((kv&7)<<4))) = pk.u;
      const float vv[4] = {vx.x, vx.y, vx.z, vx.w};
#pragma unroll
      for (int c = 0; c < 4; ++c) {
        const int d = sc4*4 + c;
        *(ushort*)((char*)vbuf + d*128 + ((kv*2) ^ ((d&7)<<4))) = bfb(vv[c]);
      }
    }
    __syncthreads();

    // ---- mask loads (int32, L3-resident), at C-layout positions ----
    int mv[4][4];
#pragma unroll
    for (int r = 0; r < 4; ++r) {
      const int qg = q0 + w*16 + kg*4 + r;
#pragma unroll
      for (int ct = 0; ct < 4; ++ct)
        mv[r][ct] = M[(size_t)qg * S_LEN + kv0 + ct*16 + qr];
    }

    // ---- S = (Q/8) K^T : 4 column-tiles x 2 k-steps ----
    f32x4 sc[4];
#pragma unroll
    for (int ct = 0; ct < 4; ++ct) {
      f32x4 z = {0.f,0.f,0.f,0.f};
      sc[ct] = z;
#pragma unroll
      for (int ks = 0; ks < 2; ++ks) {
        const int krow = 16*ct + qr;
        bf16x8 kf = *(const bf16x8*)((const char*)kbuf + krow*128 +
                        ((kg*16 + 64*ks) ^ ((krow&7)<<4)));
        sc[ct] = __builtin_amdgcn_mfma_f32_16x16x32_bf16(qf[ks], kf, sc[ct], 0,0,0);
      }
    }

    // ---- online softmax (C-layout: q = kg*4+r, kv = qr+16*ct) ----
    float pv[4][4];
#pragma unroll
    for (int r = 0; r < 4; ++r) {
      float s0 = mv[r][0] ? sc[0][r] : -1e9f;
      float s1 = mv[r][1] ? sc[1][r] : -1e9f;
      float s2 = mv[r][2] ? sc[2][r] : -1e9f;
      float s3 = mv[r][3] ? sc[3][r] : -1e9f;
      float rm = redmax16(fmaxf(fmaxf(s0,s1), fmaxf(s2,s3)));
      const float mnew = fmaxf(mrow[r], rm);
      const float corr = __builtin_amdgcn_exp2f((mrow[r]-mnew)*LOG2E);
      mrow[r] = mnew;
      const float p0 = __builtin_amdgcn_exp2f((s0-mnew)*LOG2E);
      const float p1 = __builtin_amdgcn_exp2f((s1-mnew)*LOG2E);
      const float p2 = __builtin_amdgcn_exp2f((s2-mnew)*LOG2E);
      const float p3 = __builtin_amdgcn_exp2f((s3-mnew)*LOG2E);
      rsum[r] = rsum[r]*corr + redsum16(p0+p1+p2+p3);
      pv[r][0]=p0; pv[r][1]=p1; pv[r][2]=p2; pv[r][3]=p3;
      acc[0][r]*=corr; acc[1][r]*=corr; acc[2][r]*=corr; acc[3][r]*=corr;
    }

    // ---- P -> per-wave LDS (swizzled); same-wave hazard only ----
#pragma unroll
    for (int r = 0; r < 4; ++r) {
      const int qrow = kg*4 + r;
      char* pb = (char*)pbuf + (w*16 + qrow)*128;
#pragma unroll
      for (int ct = 0; ct < 4; ++ct)
        *(ushort*)(pb + (((qr + 16*ct)*2) ^ ((qrow&7)<<4))) = bfb(pv[r][ct]);
    }

    // ---- O += P V ----
#pragma unroll
    for (int ks = 0; ks < 2; ++ks) {
      bf16x8 pf = *(const bf16x8*)((const char*)pbuf + (w*16+qr)*128 +
                      ((kg*16 + 64*ks) ^ ((qr&7)<<4)));
#pragma unroll
      for (int nt = 0; nt < 4; ++nt) {
        const int vrow = 16*nt + qr;
        bf16x8 vf = *(const bf16x8*)((const char*)vbuf + vrow*128 +
                        ((kg*16 + 64*ks) ^ ((vrow&7)<<4)));
        acc[nt] = __builtin_amdgcn_mfma_f32_16x16x32_bf16(pf, vf, acc[nt], 0,0,0);
      }
    }
  }

  // ---- epilogue: O = acc / rsum ----
  float* Ob = O + ((size_t)bh * S_LEN + q0 + w*16) * DH;
#pragma unroll
  for (int r = 0; r < 4; ++r) {
    const float inv = 1.0f / rsum[r];
#pragma unroll
    for (int nt = 0; nt < 4; ++nt)
      Ob[(kg*4 + r)*DH + 16*nt + qr] = acc[nt][r] * inv;
  }
}

extern "C" void kernel_launch(void* const* d_in, const int* in_sizes, int n_in,
                              void* d_out, int out_size, void* d_ws, size_t ws_size,
                              hipStream_t stream)
{
  const float* Q = (const float*)d_in[0];
  const float* K = (const float*)d_in[1];
  const float* V = (const float*)d_in[2];
  const int*   M = (const int*)d_in[3];
  float* O = (float*)d_out;

  dim3 grid(S_LEN / QBLK, 4 * 16);   // 32 q-blocks x 64 (b,h)
  attn_fwd<<<grid, NWAVE * 64, 0, stream>>>(Q, K, V, M, O);
}

// Round 2
// 272.521 us; speedup vs baseline: 1.2315x; 1.2315x over previous
//
#include <hip/hip_runtime.h>

typedef __bf16 bf16;
typedef __attribute__((ext_vector_type(8))) __bf16 bf16x8;
typedef __attribute__((ext_vector_type(8))) ushort ushort8v;
typedef __attribute__((ext_vector_type(4))) ushort ushort4v;
typedef __attribute__((ext_vector_type(4))) float f32x4;

constexpr int S_LEN = 2048;
constexpr int DH    = 64;
constexpr int QBLK  = 64;
constexpr int KVBLK = 64;
constexpr int NWAVE = 4;
// scores computed in log2 domain: fold 1/sqrt(64) * log2(e) into Q
constexpr float QSCALE = 0.125f * 1.44269504088896f;
constexpr float NEG    = -1.44269504e9f;   // -1e9 in log2 domain

__device__ __forceinline__ ushort bfb(float f) {
  bf16 b = (bf16)f;
  return __builtin_bit_cast(ushort, b);
}
// XOR-swizzle: keys on row bits 0..2 XOR 3..5 so every staging/read pattern
// spreads across 8 16B-granules (32 banks). Applied identically on write+read.
__device__ __forceinline__ int SWZ(int row) {
  return ((row & 7) ^ ((row >> 3) & 7)) << 4;
}

__device__ __forceinline__ float redmax16(float x) {
  x = fmaxf(x, __shfl_xor(x, 1));
  x = fmaxf(x, __shfl_xor(x, 2));
  x = fmaxf(x, __shfl_xor(x, 4));
  x = fmaxf(x, __shfl_xor(x, 8));
  return x;
}
__device__ __forceinline__ float redsum16(float x) {
  x += __shfl_xor(x, 1);
  x += __shfl_xor(x, 2);
  x += __shfl_xor(x, 4);
  x += __shfl_xor(x, 8);
  return x;
}

// ---- pre-kernel: per 64x64 tile, flag = (all mask entries nonzero) ----
__global__ __launch_bounds__(256)
void mask_flags(const int* __restrict__ M, int* __restrict__ F) {
  const int qt = blockIdx.x, kt = blockIdx.y;
  const int tid = threadIdx.x;
  const int r  = tid >> 2;
  const int c0 = (tid & 3) * 16;
  const int* row = M + (size_t)(qt * 64 + r) * S_LEN + kt * 64 + c0;
  int ok = 1;
#pragma unroll
  for (int i = 0; i < 4; ++i) {
    int4 v = *(const int4*)(row + i * 4);
    ok &= (v.x != 0) & (v.y != 0) & (v.z != 0) & (v.w != 0);
  }
  ok = __all(ok) ? 1 : 0;
  __shared__ int s[4];
  if ((tid & 63) == 0) s[tid >> 6] = ok;
  __syncthreads();
  if (tid == 0) F[qt * 32 + kt] = s[0] & s[1] & s[2] & s[3];
}

__global__ __launch_bounds__(256)
void attn_fwd(const float* __restrict__ Q, const float* __restrict__ K,
              const float* __restrict__ V, const int* __restrict__ M,
              const int* __restrict__ F, float* __restrict__ O)
{
  __shared__ __align__(16) ushort kbuf[KVBLK * DH];      // [kv][d] swizzled
  __shared__ __align__(16) ushort vbuf[DH * KVBLK];      // [d][kv] swizzled
  __shared__ __align__(16) ushort pbuf[NWAVE * 16 * KVBLK];
  __shared__ int fl[32];

  const int tid  = threadIdx.x;
  const int lane = tid & 63;
  const int w    = tid >> 6;
  const int qr   = lane & 15;
  const int kg   = lane >> 4;

  const int q0 = blockIdx.x * QBLK;
  const int bh = blockIdx.y;

  const float* Qb = Q + ((size_t)bh * S_LEN) * DH;
  const float* Kb = K + ((size_t)bh * S_LEN) * DH;
  const float* Vb = V + ((size_t)bh * S_LEN) * DH;

  if (F && tid < 32) fl[tid] = F[blockIdx.x * 32 + tid];

  // ---- Q fragments, pre-scaled into log2 domain ----
  bf16x8 qf[2];
  {
    const float* qp = Qb + (size_t)(q0 + w * 16 + qr) * DH + kg * 8;
#pragma unroll
    for (int ks = 0; ks < 2; ++ks) {
      float4 a = *(const float4*)(qp + ks * 32);
      float4 b = *(const float4*)(qp + ks * 32 + 4);
      bf16x8 t2;
      t2[0]=(bf16)(a.x*QSCALE); t2[1]=(bf16)(a.y*QSCALE);
      t2[2]=(bf16)(a.z*QSCALE); t2[3]=(bf16)(a.w*QSCALE);
      t2[4]=(bf16)(b.x*QSCALE); t2[5]=(bf16)(b.y*QSCALE);
      t2[6]=(bf16)(b.z*QSCALE); t2[7]=(bf16)(b.w*QSCALE);
      qf[ks] = t2;
    }
  }

  f32x4 acc[4];
#pragma unroll
  for (int nt = 0; nt < 4; ++nt) { f32x4 z = {0.f,0.f,0.f,0.f}; acc[nt] = z; }
  float mrow[4] = {-1e30f,-1e30f,-1e30f,-1e30f};
  float rsum[4] = {0.f,0.f,0.f,0.f};

  // staging decomposition
  const int kr0 = tid >> 3;        // K: row 0..31 (+32 for chunk 1)
  const int kc8 = tid & 7;         // K: 8-float col group
  const int vr  = (tid >> 4) * 4;  // V: 4 consecutive kv rows
  const int vc  = (tid & 15) * 4;  // V: 4 consecutive d cols

  for (int t = 0; t < S_LEN / KVBLK; ++t) {
    const int kv0 = t * KVBLK;
    __syncthreads();   // prev tile reads done (also covers fl staging at t=0)

    // ---- stage K: one b128 per chunk, swizzled, conflict-minimal ----
#pragma unroll
    for (int h = 0; h < 2; ++h) {
      const int row = kr0 + 32 * h;
      const float* kp = Kb + (size_t)(kv0 + row) * DH + kc8 * 8;
      float4 a = *(const float4*)kp;
      float4 b = *(const float4*)(kp + 4);
      ushort8v pk;
      pk[0]=bfb(a.x); pk[1]=bfb(a.y); pk[2]=bfb(a.z); pk[3]=bfb(a.w);
      pk[4]=bfb(b.x); pk[5]=bfb(b.y); pk[6]=bfb(b.z); pk[7]=bfb(b.w);
      *(ushort8v*)((char*)kbuf + row * 128 + ((kc8 * 16) ^ SWZ(row))) = pk;
    }
    // ---- stage V: 4x4 register transpose -> 4 b64 writes ----
    {
      float rr[4][4];
#pragma unroll
      for (int i = 0; i < 4; ++i)
        *(float4*)rr[i] = *(const float4*)(Vb + (size_t)(kv0 + vr + i) * DH + vc);
#pragma unroll
      for (int c = 0; c < 4; ++c) {
        const int d = vc + c;
        ushort4v p4;
        p4[0]=bfb(rr[0][c]); p4[1]=bfb(rr[1][c]);
        p4[2]=bfb(rr[2][c]); p4[3]=bfb(rr[3][c]);
        *(ushort4v*)((char*)vbuf + d * 128 + ((vr * 2) ^ SWZ(d))) = p4;
      }
    }
    __syncthreads();

    const bool allset = F ? (fl[t] != 0) : false;
    int mv[4][4];
    if (!allset) {
#pragma unroll
      for (int r = 0; r < 4; ++r) {
        const int qg = q0 + w * 16 + kg * 4 + r;
#pragma unroll
        for (int ct = 0; ct < 4; ++ct)
          mv[r][ct] = M[(size_t)qg * S_LEN + kv0 + ct * 16 + qr];
      }
    }

    // ---- S(log2) = Q K^T ----
    f32x4 sc[4];
#pragma unroll
    for (int ct = 0; ct < 4; ++ct) {
      f32x4 z = {0.f,0.f,0.f,0.f};
      sc[ct] = z;
#pragma unroll
      for (int ks = 0; ks < 2; ++ks) {
        const int krow = 16 * ct + qr;
        bf16x8 kf = *(const bf16x8*)((const char*)kbuf + krow * 128 +
                        ((kg * 16 + 64 * ks) ^ SWZ(krow)));
        sc[ct] = __builtin_amdgcn_mfma_f32_16x16x32_bf16(qf[ks], kf, sc[ct], 0,0,0);
      }
    }

    // ---- online softmax (log2 domain) ----
    float pv[4][4];
#pragma unroll
    for (int r = 0; r < 4; ++r) {
      float s0 = sc[0][r], s1 = sc[1][r], s2 = sc[2][r], s3 = sc[3][r];
      if (!allset) {
        if (!mv[r][0]) s0 = NEG;
        if (!mv[r][1]) s1 = NEG;
        if (!mv[r][2]) s2 = NEG;
        if (!mv[r][3]) s3 = NEG;
      }
      float rm = redmax16(fmaxf(fmaxf(s0,s1), fmaxf(s2,s3)));
      const float mnew = fmaxf(mrow[r], rm);
      const float corr = __builtin_amdgcn_exp2f(mrow[r] - mnew);
      mrow[r] = mnew;
      const float p0 = __builtin_amdgcn_exp2f(s0 - mnew);
      const float p1 = __builtin_amdgcn_exp2f(s1 - mnew);
      const float p2 = __builtin_amdgcn_exp2f(s2 - mnew);
      const float p3 = __builtin_amdgcn_exp2f(s3 - mnew);
      rsum[r] = rsum[r] * corr + redsum16(p0 + p1 + p2 + p3);
      pv[r][0]=p0; pv[r][1]=p1; pv[r][2]=p2; pv[r][3]=p3;
      acc[0][r]*=corr; acc[1][r]*=corr; acc[2][r]*=corr; acc[3][r]*=corr;
    }

    // ---- P -> per-wave LDS (swizzled) ----
#pragma unroll
    for (int r = 0; r < 4; ++r) {
      const int row = w * 16 + kg * 4 + r;
      char* pb = (char*)pbuf + row * 128;
      const int sw = SWZ(row);
#pragma unroll
      for (int ct = 0; ct < 4; ++ct)
        *(ushort*)(pb + (((qr + 16 * ct) * 2) ^ sw)) = bfb(pv[r][ct]);
    }

    // ---- O += P V ----
#pragma unroll
    for (int ks = 0; ks < 2; ++ks) {
      const int prow = w * 16 + qr;
      bf16x8 pf = *(const bf16x8*)((const char*)pbuf + prow * 128 +
                      ((kg * 16 + 64 * ks) ^ SWZ(prow)));
#pragma unroll
      for (int nt = 0; nt < 4; ++nt) {
        const int vrow = 16 * nt + qr;
        bf16x8 vf = *(const bf16x8*)((const char*)vbuf + vrow * 128 +
                        ((kg * 16 + 64 * ks) ^ SWZ(vrow)));
        acc[nt] = __builtin_amdgcn_mfma_f32_16x16x32_bf16(pf, vf, acc[nt], 0,0,0);
      }
    }
  }

  // ---- epilogue ----
  float* Ob = O + ((size_t)bh * S_LEN + q0 + w * 16) * DH;
#pragma unroll
  for (int r = 0; r < 4; ++r) {
    const float inv = 1.0f / rsum[r];
#pragma unroll
    for (int nt = 0; nt < 4; ++nt)
      Ob[(kg * 4 + r) * DH + 16 * nt + qr] = acc[nt][r] * inv;
  }
}

extern "C" void kernel_launch(void* const* d_in, const int* in_sizes, int n_in,
                              void* d_out, int out_size, void* d_ws, size_t ws_size,
                              hipStream_t stream)
{
  const float* Q = (const float*)d_in[0];
  const float* K = (const float*)d_in[1];
  const float* V = (const float*)d_in[2];
  const int*   M = (const int*)d_in[3];
  float* O = (float*)d_out;

  int* F = (ws_size >= 32 * 32 * sizeof(int)) ? (int*)d_ws : nullptr;
  if (F) mask_flags<<<dim3(32, 32), 256, 0, stream>>>(M, F);

  dim3 grid(S_LEN / QBLK, 4 * 16);
  attn_fwd<<<grid, NWAVE * 64, 0, stream>>>(Q, K, V, M, F, O);
}

// Round 3
// 165.561 us; speedup vs baseline: 2.0271x; 1.6460x over previous
//
#include <hip/hip_runtime.h>

typedef __bf16 bf16;
typedef __attribute__((ext_vector_type(8))) __bf16 bf16x8;
typedef __attribute__((ext_vector_type(8))) ushort ushort8v;
typedef __attribute__((ext_vector_type(4))) ushort ushort4v;
typedef __attribute__((ext_vector_type(2))) uint uint2v;
typedef __attribute__((ext_vector_type(4))) float f32x4;

constexpr int S_LEN = 2048;
constexpr int DH    = 64;
constexpr int QBLK  = 64;
constexpr int KVBLK = 64;
constexpr int NWAVE = 4;
constexpr int NT    = S_LEN / KVBLK;            // 32 kv tiles
constexpr float QSCALE = 0.125f * 1.44269504088896f;  // 1/sqrt(64) * log2(e)
constexpr float NEG    = -1.44269504e9f;        // -1e9 in log2 domain
constexpr float THR    = 8.0f;                  // defer-max threshold (T13)
constexpr size_t TILE_BYTES = (size_t)KVBLK * DH * 2;      // 8 KiB
constexpr size_t KV_BYTES   = (size_t)64 * NT * TILE_BYTES; // 16 MiB per tensor

__device__ __forceinline__ ushort bfb(float f) {
  bf16 b = (bf16)f;
  return __builtin_bit_cast(ushort, b);
}
__device__ __forceinline__ int SWZ(int row) {
  return ((row & 7) ^ ((row >> 3) & 7)) << 4;
}
__device__ __forceinline__ uint cvtpk(float lo, float hi) {
  uint r;
  asm("v_cvt_pk_bf16_f32 %0, %1, %2" : "=v"(r) : "v"(lo), "v"(hi));
  return r;
}
__device__ __forceinline__ void gload16(const char* g, void* l) {
  __builtin_amdgcn_global_load_lds(
      (__attribute__((address_space(1))) void*)(g),
      (__attribute__((address_space(3))) void*)(l), 16, 0, 0);
}

// ---- prepass: per 64x64 mask tile, flag = all-nonzero ----
__global__ __launch_bounds__(256)
void mask_flags(const int* __restrict__ M, int* __restrict__ F) {
  const int qt = blockIdx.x, kt = blockIdx.y;
  const int tid = threadIdx.x;
  const int r  = tid >> 2;
  const int c0 = (tid & 3) * 16;
  const int* row = M + (size_t)(qt * 64 + r) * S_LEN + kt * 64 + c0;
  int ok = 1;
#pragma unroll
  for (int i = 0; i < 4; ++i) {
    int4 v = *(const int4*)(row + i * 4);
    ok &= (v.x != 0) & (v.y != 0) & (v.z != 0) & (v.w != 0);
  }
  ok = __all(ok) ? 1 : 0;
  __shared__ int s[4];
  if ((tid & 63) == 0) s[tid >> 6] = ok;
  __syncthreads();
  if (tid == 0) F[qt * 32 + kt] = s[0] & s[1] & s[2] & s[3];
}

// ---- prepass: K -> bf16 swizzled tile blobs; V -> V^T bf16 swizzled blobs ----
__global__ __launch_bounds__(256)
void cvt_kv(const float* __restrict__ K, const float* __restrict__ V,
            char* __restrict__ kws, char* __restrict__ vws) {
  const int t = blockIdx.x, bh = blockIdx.y, tid = threadIdx.x;
  const float* Kb = K + ((size_t)bh * S_LEN + t * KVBLK) * DH;
  const float* Vb = V + ((size_t)bh * S_LEN + t * KVBLK) * DH;
  char* kd = kws + ((size_t)bh * NT + t) * TILE_BYTES;
  char* vd = vws + ((size_t)bh * NT + t) * TILE_BYTES;

  const int kr0 = tid >> 3, kc8 = tid & 7;
#pragma unroll
  for (int h = 0; h < 2; ++h) {
    const int row = kr0 + 32 * h;
    const float* kp = Kb + (size_t)row * DH + kc8 * 8;
    float4 a = *(const float4*)kp;
    float4 b = *(const float4*)(kp + 4);
    ushort8v pk;
    pk[0]=bfb(a.x); pk[1]=bfb(a.y); pk[2]=bfb(a.z); pk[3]=bfb(a.w);
    pk[4]=bfb(b.x); pk[5]=bfb(b.y); pk[6]=bfb(b.z); pk[7]=bfb(b.w);
    *(ushort8v*)(kd + row * 128 + ((kc8 * 16) ^ SWZ(row))) = pk;
  }
  const int vr = (tid >> 4) * 4, vc = (tid & 15) * 4;
  float rr[4][4];
#pragma unroll
  for (int i = 0; i < 4; ++i)
    *(float4*)rr[i] = *(const float4*)(Vb + (size_t)(vr + i) * DH + vc);
#pragma unroll
  for (int c = 0; c < 4; ++c) {
    const int d = vc + c;
    ushort4v p4;
    p4[0]=bfb(rr[0][c]); p4[1]=bfb(rr[1][c]);
    p4[2]=bfb(rr[2][c]); p4[3]=bfb(rr[3][c]);
    *(ushort4v*)(vd + d * 128 + ((vr * 2) ^ SWZ(d))) = p4;
  }
}

template<bool PRE>
__global__ __launch_bounds__(256)
void attn_fwd(const float* __restrict__ Q, const float* __restrict__ K,
              const float* __restrict__ V, const int* __restrict__ M,
              const int* __restrict__ F, const char* __restrict__ kws,
              const char* __restrict__ vws, float* __restrict__ O)
{
  __shared__ __align__(16) ushort kb[2][KVBLK * DH];   // [kv][d] swizzled
  __shared__ __align__(16) ushort vb[2][DH * KVBLK];   // [d][kv] swizzled
  __shared__ __align__(16) uint   pbw[NWAVE * 16 * 32]; // per-wave P^T words
  __shared__ int fl[NT];

  const int tid  = threadIdx.x;
  const int lane = tid & 63;
  const int w    = tid >> 6;
  const int qr   = lane & 15;
  const int kg   = lane >> 4;

  // XCD-aware bijective block swizzle (2048 % 8 == 0)
  const int flat = blockIdx.y * gridDim.x + blockIdx.x;
  const int nid  = (flat & 7) * 256 + (flat >> 3);
  const int q0   = (nid & 31) * QBLK;
  const int bh   = nid >> 5;

  const float* Qb = Q + ((size_t)bh * S_LEN) * DH;
  const float* Kb = K + ((size_t)bh * S_LEN) * DH;
  const float* Vb = V + ((size_t)bh * S_LEN) * DH;

  if (PRE && tid < NT) fl[tid] = F[(q0 / QBLK) * 32 + tid];

  // ---- Q fragments (A/B lane maps coincide; reused as B for swapped QK^T) ----
  bf16x8 qf[2];
  {
    const float* qp = Qb + (size_t)(q0 + w * 16 + qr) * DH + kg * 8;
#pragma unroll
    for (int ks = 0; ks < 2; ++ks) {
      float4 a = *(const float4*)(qp + ks * 32);
      float4 b = *(const float4*)(qp + ks * 32 + 4);
      bf16x8 t2;
      t2[0]=(bf16)(a.x*QSCALE); t2[1]=(bf16)(a.y*QSCALE);
      t2[2]=(bf16)(a.z*QSCALE); t2[3]=(bf16)(a.w*QSCALE);
      t2[4]=(bf16)(b.x*QSCALE); t2[5]=(bf16)(b.y*QSCALE);
      t2[6]=(bf16)(b.z*QSCALE); t2[7]=(bf16)(b.w*QSCALE);
      qf[ks] = t2;
    }
  }

  f32x4 acc[4];
#pragma unroll
  for (int nt = 0; nt < 4; ++nt) { f32x4 z = {0.f,0.f,0.f,0.f}; acc[nt] = z; }
  float mrow = -1e30f;   // running max of row q = q0 + w*16 + qr (log2 domain)
  float rsum = 0.f;      // per-lane partial row sum (reduced at epilogue)

  // staging decomposition for the non-prepass fallback
  const int kr0 = tid >> 3, kc8 = tid & 7;
  const int vr = (tid >> 4) * 4, vc = (tid & 15) * 4;

  // ---- staging: PRE = 4x global_load_lds dwordx4 per wave, zero VALU ----
  auto stage = [&](int buf, int t) {
    if (PRE) {
      const char* ks = kws + ((size_t)bh * NT + t) * TILE_BYTES;
      const char* vs = vws + ((size_t)bh * NT + t) * TILE_BYTES;
#pragma unroll
      for (int c = 0; c < 2; ++c) {
        const int off = (w + c * 4) * 1024 + lane * 16;
        gload16(ks + off, (char*)kb[buf] + off);
        gload16(vs + off, (char*)vb[buf] + off);
      }
    } else {
      const int kv0 = t * KVBLK;
#pragma unroll
      for (int h = 0; h < 2; ++h) {
        const int row = kr0 + 32 * h;
        const float* kp = Kb + (size_t)(kv0 + row) * DH + kc8 * 8;
        float4 a = *(const float4*)kp;
        float4 b = *(const float4*)(kp + 4);
        ushort8v pk;
        pk[0]=bfb(a.x); pk[1]=bfb(a.y); pk[2]=bfb(a.z); pk[3]=bfb(a.w);
        pk[4]=bfb(b.x); pk[5]=bfb(b.y); pk[6]=bfb(b.z); pk[7]=bfb(b.w);
        *(ushort8v*)((char*)kb[buf] + row * 128 + ((kc8 * 16) ^ SWZ(row))) = pk;
      }
      float rr[4][4];
#pragma unroll
      for (int i = 0; i < 4; ++i)
        *(float4*)rr[i] = *(const float4*)(Vb + (size_t)(kv0 + vr + i) * DH + vc);
#pragma unroll
      for (int c = 0; c < 4; ++c) {
        const int d = vc + c;
        ushort4v p4;
        p4[0]=bfb(rr[0][c]); p4[1]=bfb(rr[1][c]);
        p4[2]=bfb(rr[2][c]); p4[3]=bfb(rr[3][c]);
        *(ushort4v*)((char*)vb[buf] + d * 128 + ((vr * 2) ^ SWZ(d))) = p4;
      }
    }
  };

  int cur = 0;
  stage(0, 0);
  __syncthreads();

  char* pb = (char*)pbw + (w * 16 + qr) * 128;   // this lane's P^T row
  const int psw = (qr & 7) << 4;                 // P row swizzle key

  for (int t = 0; t < NT; ++t) {
    const int kv0 = t * KVBLK;
    if (t + 1 < NT) stage(cur ^ 1, t + 1);   // prefetch overlaps compute

    // ---- S^T = K Q^T : lane holds S[q=qr][kv = kv0 + 16ct + 4kg + r] ----
    f32x4 sc[4];
#pragma unroll
    for (int ct = 0; ct < 4; ++ct) {
      f32x4 z = {0.f,0.f,0.f,0.f};
      sc[ct] = z;
#pragma unroll
      for (int ks = 0; ks < 2; ++ks) {
        const int krow = 16 * ct + qr;
        bf16x8 kf = *(const bf16x8*)((const char*)kb[cur] + krow * 128 +
                        ((kg * 16 + 64 * ks) ^ SWZ(krow)));
        sc[ct] = __builtin_amdgcn_mfma_f32_16x16x32_bf16(kf, qf[ks], sc[ct], 0,0,0);
      }
    }

    // ---- mask fallback (skipped when tile flag says all-ones) ----
    const bool allset = PRE ? (fl[t] != 0) : false;
    if (!allset) {
      const size_t mrowoff = (size_t)(q0 + w * 16 + qr) * S_LEN + kv0 + 4 * kg;
#pragma unroll
      for (int ct = 0; ct < 4; ++ct)
#pragma unroll
        for (int r = 0; r < 4; ++r)
          if (M[mrowoff + 16 * ct + r] == 0) sc[ct][r] = NEG;
    }

    // ---- in-register online softmax (lane-local row slice) ----
    float lm = fmaxf(fmaxf(fmaxf(sc[0][0], sc[0][1]), fmaxf(sc[0][2], sc[0][3])),
                     fmaxf(fmaxf(sc[1][0], sc[1][1]), fmaxf(sc[1][2], sc[1][3])));
    lm = fmaxf(lm,
         fmaxf(fmaxf(fmaxf(sc[2][0], sc[2][1]), fmaxf(sc[2][2], sc[2][3])),
               fmaxf(fmaxf(sc[3][0], sc[3][1]), fmaxf(sc[3][2], sc[3][3]))));
    lm = fmaxf(lm, __shfl_xor(lm, 16));
    lm = fmaxf(lm, __shfl_xor(lm, 32));   // uniform across the row's 4 lanes

    if (!__all(lm - mrow <= THR)) {       // defer-max: rescale only when needed
      const float mnew = fmaxf(mrow, lm);
      const float corr = __builtin_amdgcn_exp2f(mrow - mnew);
      rsum *= corr;
#pragma unroll
      for (int nt = 0; nt < 4; ++nt) acc[nt] *= corr;
      mrow = mnew;
    }

    float p[4][4];
    float ps = 0.f;
#pragma unroll
    for (int ct = 0; ct < 4; ++ct) {
#pragma unroll
      for (int r = 0; r < 4; ++r) {
        p[ct][r] = __builtin_amdgcn_exp2f(sc[ct][r] - mrow);
        ps += p[ct][r];
      }
    }
    rsum += ps;

    // ---- P^T -> packed u32 words in LDS (4x ds_write_b64, ~conflict-free) ----
#pragma unroll
    for (int ct = 0; ct < 4; ++ct) {
      uint2v d2;
      d2[0] = cvtpk(p[ct][0], p[ct][1]);
      d2[1] = cvtpk(p[ct][2], p[ct][3]);
      *(uint2v*)(pb + ((32 * ct + 8 * kg) ^ psw)) = d2;
    }

    // ---- O^T += V^T P^T ----
#pragma unroll
    for (int ks = 0; ks < 2; ++ks) {
      bf16x8 pf = *(const bf16x8*)(pb + ((kg * 16 + 64 * ks) ^ psw));
#pragma unroll
      for (int nt = 0; nt < 4; ++nt) {
        const int vrow = 16 * nt + qr;
        bf16x8 vf = *(const bf16x8*)((const char*)vb[cur] + vrow * 128 +
                        ((kg * 16 + 64 * ks) ^ SWZ(vrow)));
        acc[nt] = __builtin_amdgcn_mfma_f32_16x16x32_bf16(vf, pf, acc[nt], 0,0,0);
      }
    }

    __syncthreads();   // all reads of cur done; prefetch into cur^1 landed
    cur ^= 1;
  }

  // ---- epilogue: reduce rsum across the row's 4 lanes, packed stores ----
  rsum += __shfl_xor(rsum, 16);
  rsum += __shfl_xor(rsum, 32);
  const float inv = 1.0f / rsum;
  float* Ob = O + ((size_t)bh * S_LEN + q0 + w * 16 + qr) * DH;
#pragma unroll
  for (int nt = 0; nt < 4; ++nt) {
    float4 o = { acc[nt][0] * inv, acc[nt][1] * inv,
                 acc[nt][2] * inv, acc[nt][3] * inv };
    *(float4*)(Ob + 16 * nt + 4 * kg) = o;
  }
}

extern "C" void kernel_launch(void* const* d_in, const int* in_sizes, int n_in,
                              void* d_out, int out_size, void* d_ws, size_t ws_size,
                              hipStream_t stream)
{
  const float* Q = (const float*)d_in[0];
  const float* K = (const float*)d_in[1];
  const float* V = (const float*)d_in[2];
  const int*   M = (const int*)d_in[3];
  float* O = (float*)d_out;

  const size_t need = 4096 + 2 * KV_BYTES;
  const bool pre = (d_ws != nullptr) && (ws_size >= need);

  dim3 grid(S_LEN / QBLK, 4 * 16);
  if (pre) {
    int*  F   = (int*)d_ws;
    char* kws = (char*)d_ws + 4096;
    char* vws = kws + KV_BYTES;
    mask_flags<<<dim3(32, 32), 256, 0, stream>>>(M, F);
    cvt_kv<<<dim3(NT, 64), 256, 0, stream>>>(K, V, kws, vws);
    attn_fwd<true><<<grid, NWAVE * 64, 0, stream>>>(Q, K, V, M, F, kws, vws, O);
  } else {
    attn_fwd<false><<<grid, NWAVE * 64, 0, stream>>>(Q, K, V, M, nullptr, nullptr, nullptr, O);
  }
}